// Round 12
// baseline (495.631 us; speedup 1.0000x reference)
//
#include <hip/hip_runtime.h>
#include <math.h>

// PhaseRefinement fused kernel, v12: traffic-reduced work split.
// R11's decisive result: forcing MLP=12 changed nothing (412 vs 415 us,
// duty ~12%/wave in BOTH) -> not latency-bound; the vector-memory path is
// throughput-saturated (~41 B/cyc/CU ~ 2/3 of the L2 ceiling). Only traffic
// reduction helps. v12 re-splits work: 16 rows/block, 8 waves = 2 row-groups
// x 4 plane-groups; each wave 8 rows x 8 planes (acc=64). Per-CU main-loop
// traffic 26 -> 18.5 MB (x redundancy 8->4, W amortized over 2x rows);
// FMA:load 256:16 (2x R5). Loads stay ordered volatile asm (R11 machinery),
// split wait vmcnt(4)/vmcnt(0) to cap live regs ~175 @ launch_bounds(512,1).
//
// out = x + LN(c*x)*gamma + beta; LN(c*x) collapses to
//   normed = gamma*(alpha*x - alpha*mu) + beta,
//   alpha = c*rsqrt(c^2*var + 1e-5), mu/var = plain row stats of x.

constexpr int Dh     = 4096;
constexpr int Ph     = 16;
constexpr int NPL    = 32;
constexpr int CHUNK  = 256;          // 64 lanes * 4 floats
constexpr int NCHUNK = Dh / CHUNK;   // 16
constexpr int RPB    = 16;           // rows per block
constexpr int NW     = 8;            // waves per block
constexpr int RW     = 8;            // rows per wave
constexpr int PW     = 8;            // planes per wave
constexpr int BLOCK  = 64 * NW;      // 512

// flat-global form: full 64-bit per-lane address in a VGPR pair.
// Volatile => program-ordered among themselves and vs the waitcnt.
__device__ __forceinline__ float4 gload_v(const float* addr) {
    float4 v;
    asm volatile("global_load_dwordx4 %0, %1, off"
                 : "=v"(v) : "v"(addr));
    return v;
}

__global__ __launch_bounds__(BLOCK, 1)
void phase_fused(const float* __restrict__ x,
                 const float* __restrict__ Wr,
                 const float* __restrict__ br,
                 const float* __restrict__ Wo,
                 const float* __restrict__ bo,
                 const float* __restrict__ gamma,
                 const float* __restrict__ beta,
                 float* __restrict__ out)
{
    __shared__ float dots_lds[RPB][NPL];
    __shared__ float stats_lds[RPB][2];
    __shared__ float scale_lds[RPB][2];

    const int t    = threadIdx.x;
    const int wv   = t >> 6;
    const int lane = t & 63;
    const int rg   = wv >> 2;          // row group 0..1
    const int pg   = wv & 3;           // plane group 0..3
    const size_t rowbase = (size_t)blockIdx.x * RPB;

    // This wave's 8 x rows (rows rg*8 .. rg*8+7), lane offset folded in.
    const float* xptr[RW];
#pragma unroll
    for (int r = 0; r < RW; ++r)
        xptr[r] = x + (rowbase + rg * RW + r) * (size_t)Dh + lane * 4;

    // This wave's 8 W planes: global plane q = pg*8+p. pg 0-1 -> Wr rows
    // pg*8..; pg 2-3 -> Wo rows (pg-2)*8.. (contiguous rows of one matrix).
    const float* wb = (pg < 2) ? (Wr + (size_t)(pg * 8) * Dh)
                               : (Wo + (size_t)((pg - 2) * 8) * Dh);
    const float* wptr[PW];
#pragma unroll
    for (int p = 0; p < PW; ++p)
        wptr[p] = wb + (size_t)p * Dh + lane * 4;

    float acc[RW][PW];
#pragma unroll
    for (int r = 0; r < RW; ++r)
#pragma unroll
        for (int p = 0; p < PW; ++p) acc[r][p] = 0.f;
    // Stats: wave (rg,pg) owns local rows 2pg, 2pg+1 (static indices).
    float sx[2]  = {0.f, 0.f};
    float sxx[2] = {0.f, 0.f};

#pragma unroll 1
    for (int c = 0; c < NCHUNK; ++c) {
        // 16 ordered asm loads; split wait keeps peak live regs bounded.
        float4 x4[RW];
#pragma unroll
        for (int r = 0; r < RW; ++r) x4[r] = gload_v(xptr[r]);
        float4 w4a[4];
#pragma unroll
        for (int p = 0; p < 4; ++p) w4a[p] = gload_v(wptr[p]);
        float4 w4b[4];
#pragma unroll
        for (int p = 0; p < 4; ++p) w4b[p] = gload_v(wptr[4 + p]);

        asm volatile("s_waitcnt vmcnt(4)" ::: "memory");  // x + w4a complete
        __builtin_amdgcn_sched_barrier(0);

#pragma unroll
        for (int r = 0; r < RW; ++r) {
            if ((r >> 1) == pg) {   // wave-uniform; r static
                sx[r & 1]  += x4[r].x + x4[r].y + x4[r].z + x4[r].w;
                sxx[r & 1] += x4[r].x*x4[r].x + x4[r].y*x4[r].y
                            + x4[r].z*x4[r].z + x4[r].w*x4[r].w;
            }
#pragma unroll
            for (int p = 0; p < 4; ++p)
                acc[r][p] += x4[r].x*w4a[p].x + x4[r].y*w4a[p].y
                           + x4[r].z*w4a[p].z + x4[r].w*w4a[p].w;
        }

        asm volatile("s_waitcnt vmcnt(0)" ::: "memory");  // w4b complete
        __builtin_amdgcn_sched_barrier(0);

#pragma unroll
        for (int r = 0; r < RW; ++r)
#pragma unroll
            for (int p = 0; p < 4; ++p)
                acc[r][4 + p] += x4[r].x*w4b[p].x + x4[r].y*w4b[p].y
                               + x4[r].z*w4b[p].z + x4[r].w*w4b[p].w;

#pragma unroll
        for (int r = 0; r < RW; ++r) xptr[r] += CHUNK;
#pragma unroll
        for (int p = 0; p < PW; ++p) wptr[p] += CHUNK;
    }

    // Butterfly-reduce 64 accumulators + 4 stats across the 64 lanes.
#pragma unroll
    for (int r = 0; r < RW; ++r)
#pragma unroll
        for (int p = 0; p < PW; ++p) {
            float v = acc[r][p];
#pragma unroll
            for (int m = 1; m < 64; m <<= 1) v += __shfl_xor(v, m, 64);
            if (lane == 0) dots_lds[rg * RW + r][pg * PW + p] = v;
        }
#pragma unroll
    for (int i = 0; i < 2; ++i) {
#pragma unroll
        for (int m = 1; m < 64; m <<= 1) {
            sx[i]  += __shfl_xor(sx[i], m, 64);
            sxx[i] += __shfl_xor(sxx[i], m, 64);
        }
        if (lane == 0) {
            stats_lds[rg * RW + 2 * pg + i][0] = sx[i];
            stats_lds[rg * RW + 2 * pg + i][1] = sxx[i];
        }
    }
    __syncthreads();

    // Scalar phase, parallel over (row, plane): 256 threads, 16-lane reduce.
    if (t < RPB * Ph) {
        const int r = t >> 4, p = t & 15;
        float d1 = dots_lds[r][p]      + br[p];
        float d2 = dots_lds[r][Ph + p] + bo[p];
        float cd = cosf((tanhf(d1) - tanhf(d2)) * 3.14159265358979323846f);
#pragma unroll
        for (int m = 1; m < 16; m <<= 1) cd += __shfl_xor(cd, m, 16);
        if (p == 0) {
            float s    = cd;
            float gain = log1pf(expf(s * (1.f / Ph) + 0.5f));  // softplus
            float cm   = s * gain * (1.f / Ph);
            float mu   = stats_lds[r][0] * (1.f / Dh);
            float var  = stats_lds[r][1] * (1.f / Dh) - mu * mu;
            var = fmaxf(var, 0.f);
            float rstd  = rsqrtf(cm * cm * var + 1e-5f);
            float alpha = cm * rstd;
            scale_lds[r][0] = alpha;
            scale_lds[r][1] = alpha * mu;
        }
    }
    __syncthreads();

    // Phase B, column-sliced: wave wv owns cols [wv*512, wv*512+512);
    // gamma/beta loaded ONCE per wave, reused across all 16 rows. x re-read
    // is L2-hot (FETCH_SIZE ~= x-once at HBM every round).
    {
        const int col0 = wv * 512 + lane * 4;
        const float4 g4a = *(const float4*)(gamma + col0);
        const float4 g4b = *(const float4*)(gamma + col0 + 256);
        const float4 b4a = *(const float4*)(beta  + col0);
        const float4 b4b = *(const float4*)(beta  + col0 + 256);
#pragma unroll 4
        for (int r = 0; r < RPB; ++r) {
            const float alpha = scale_lds[r][0];
            const float am    = scale_lds[r][1];
            const float* xr  = x   + (rowbase + r) * (size_t)Dh;
            float*       orw = out + (rowbase + r) * (size_t)Dh;
            float4 xa = *(const float4*)(xr + col0);
            float4 xb = *(const float4*)(xr + col0 + 256);
            float4 oa, ob;
            oa.x = xa.x + g4a.x * (alpha * xa.x - am) + b4a.x;
            oa.y = xa.y + g4a.y * (alpha * xa.y - am) + b4a.y;
            oa.z = xa.z + g4a.z * (alpha * xa.z - am) + b4a.z;
            oa.w = xa.w + g4a.w * (alpha * xa.w - am) + b4a.w;
            ob.x = xb.x + g4b.x * (alpha * xb.x - am) + b4b.x;
            ob.y = xb.y + g4b.y * (alpha * xb.y - am) + b4b.y;
            ob.z = xb.z + g4b.z * (alpha * xb.z - am) + b4b.z;
            ob.w = xb.w + g4b.w * (alpha * xb.w - am) + b4b.w;
            *(float4*)(orw + col0)       = oa;
            *(float4*)(orw + col0 + 256) = ob;
        }
    }
}

extern "C" void kernel_launch(void* const* d_in, const int* in_sizes, int n_in,
                              void* d_out, int out_size, void* d_ws, size_t ws_size,
                              hipStream_t stream)
{
    const float* x     = (const float*)d_in[0];
    const float* Wr    = (const float*)d_in[1];
    const float* br    = (const float*)d_in[2];
    const float* Wo    = (const float*)d_in[3];
    const float* bo    = (const float*)d_in[4];
    const float* gamma = (const float*)d_in[5];
    const float* beta  = (const float*)d_in[6];
    float* out = (float*)d_out;

    const int B = in_sizes[0] / Dh;       // 32768
    dim3 grid(B / RPB);                   // 2048 blocks
    phase_fused<<<grid, BLOCK, 0, stream>>>(x, Wr, br, Wo, bo, gamma, beta, out);
}